// Round 29
// baseline (28.560 us; speedup 1.0000x reference)
//
#include <hip/hip_runtime.h>

#define LEN_EPISODE 2048
#define TW 6.283185307179586
#define HH 0.16

// R29 = R28 with QUAD-EMISSION: emitters own 4-step quads (64 contiguous
// output cols = 256B/row); each flush instruction = 4 rows x 256B (vs 8 rows
// x 128B). Tests the MC/page-locality theory of the 27.5us plateau:
// 134MB at 4.9 TB/s effective vs memset's 6.5 -- halving segment count per
// byte should close the gap if DRAM page activations are the cost.
// LDS: ring 66KB + 5 emitters x [64][65] staging 83KB = 149KB < 160KB.
// Waves 6,7 exit after the init barrier (R28: emit capacity not binding).
// Producer/ring/publish/Hermite byte-identical to R28 => absmax 0.875.

#define STEPP() do {                                                        \
    const float f1 = Atil * rcf;                                            \
    const float f2 = __builtin_fmaf(nA2s, rsf, A2c * rcf);                  \
    const float f3 = __builtin_fmaf(nA3s, rsf, A3c * rcf);                  \
    rcn = __builtin_fmaf(nsdf, rsf, rcf * cdf);                             \
    rsn = __builtin_fmaf(sdf, rcf, rsf * cdf);                              \
    const float f4 = Atil * rcn;                                            \
    const float s1  = __builtin_amdgcn_sinf(U);                             \
    const float U2  = __builtin_fmaf(c13, V, U);                            \
    const float s2  = __builtin_amdgcn_sinf(U2);                            \
    const float Ub3 = __builtin_fmaf(c23, V, U);                            \
    const float s3a = __builtin_amdgcn_sinf(Ub3);                           \
    const float c3a = __builtin_amdgcn_cosf(Ub3);                           \
    const float Ub4 = __builtin_fmaf(hh, V, U);                             \
    const float s4a = __builtin_amdgcn_sinf(Ub4);                           \
    const float c4a = __builtin_amdgcn_cosf(Ub4);                           \
    const float k1w = __builtin_fmaf(nw2t, s1, __builtin_fmaf(ngam, V, f1)); \
    const float V2  = __builtin_fmaf(c13, k1w, V);                          \
    const float k2w = __builtin_fmaf(nw2t, s2, __builtin_fmaf(ngam, V2, f2)); \
    const float e3  = tph23 * k1w;                                          \
    const float s3  = __builtin_fmaf(e3, c3a,                               \
                      __builtin_fmaf(-0.5f * e3 * e3, s3a, s3a));           \
    const float V3  = __builtin_fmaf(hh, k2w, __builtin_fmaf(nc13, k1w, V)); \
    const float k3w = __builtin_fmaf(nw2t, s3, __builtin_fmaf(ngam, V3, f3)); \
    const float e4  = __builtin_fmaf(tph2, k2w, n23tph2 * k1w);             \
    const float s4  = __builtin_fmaf(e4, c4a,                               \
                      __builtin_fmaf(-0.5f * e4 * e4, s4a, s4a));           \
    const float V4  = __builtin_fmaf(hh, (k1w - k2w) + k3w, V);             \
    const float k4w = __builtin_fmaf(nw2t, s4, __builtin_fmaf(ngam, V4, f4)); \
    Un = __builtin_fmaf(h8, __builtin_fmaf(3.0f, V2 + V3, V) + V4, U);      \
    Vn = __builtin_fmaf(h8, __builtin_fmaf(3.0f, k2w + k3w, k1w) + k4w, V); \
} while (0)

// Cubic Hermite basis (compile-time doubles), radians+h folded in.
#define B00(t) ((1.0-(t))*(1.0-(t))*(1.0+2.0*(t)))
#define B10(t) ((t)*(1.0-(t))*(1.0-(t)))
#define B01(t) ((t)*(t)*(3.0-2.0*(t)))
#define B11(t) ((t)*(t)*((t)-1.0))
#define HERMT(t)                                                              \
    __builtin_fmaf((float)(TW * B00(t)), U,                                   \
    __builtin_fmaf((float)(TW * B10(t) * HH), V,                              \
    __builtin_fmaf((float)(TW * B01(t)), Un, (float)(TW * B11(t) * HH) * Vn)))

#define EMIT15(dst) do {                                                      \
    (dst)[0]  = HERMT( 1.0/16.0); (dst)[1]  = HERMT( 2.0/16.0);               \
    (dst)[2]  = HERMT( 3.0/16.0); (dst)[3]  = HERMT( 4.0/16.0);               \
    (dst)[4]  = HERMT( 5.0/16.0); (dst)[5]  = HERMT( 6.0/16.0);               \
    (dst)[6]  = HERMT( 7.0/16.0); (dst)[7]  = HERMT( 8.0/16.0);               \
    (dst)[8]  = HERMT( 9.0/16.0); (dst)[9]  = HERMT(10.0/16.0);               \
    (dst)[10] = HERMT(11.0/16.0); (dst)[11] = HERMT(12.0/16.0);               \
    (dst)[12] = HERMT(13.0/16.0); (dst)[13] = HERMT(14.0/16.0);               \
    (dst)[14] = HERMT(15.0/16.0);                                             \
} while (0)

#define COMMIT() do { U = Un; V = Vn; rcf = rcn; rsf = rsn; } while (0)

__global__ __launch_bounds__(512) void pend_kernel(
    const float* __restrict__ init,    // (B, 2)
    const float* __restrict__ params,  // (B, 4)
    float* __restrict__ out,           // (B, LEN_EPISODE)
    int B)
{
    __shared__ float2 ring[129][64];   // [state k][lane] -- written ONCE each
    __shared__ float  stag[5][64 * 65];// per-emitter staging (quads)
    __shared__ int    cnt;             // number of published states

    const int tid  = threadIdx.x;
    const int lane = tid & 63;
    const int wv   = tid >> 6;          // 0 producer; 1..5 emitters; 6,7 exit
    const int b = blockIdx.x * 64 + lane;

    const float twopi  = 6.283185307179586f;
    const float inv2pi = 0.15915494309189535f;

    const float2 ic = *reinterpret_cast<const float2*>(init + 2 * b);

    if (tid == 0) cnt = 0;
    __syncthreads();                    // cnt initialized before anyone spins

    if (wv == 0) {
        // ---------------- producer: pure integration ----------------
        const float4 p  = *reinterpret_cast<const float4*>(params + 4 * b);
        const float omega = p.x, gamma = p.y, A = p.z, phi = p.w;

        float U = ic.x * inv2pi;
        float V = ic.y * inv2pi;

        const float hh    = 0.16f;
        const float c13   = (float)(0.16 / 3.0);
        const float c23   = (float)(0.32 / 3.0);
        const float nc13  = -c13;
        const float h8    = 0.02f;
        const float tph23 = (float)(TW * 0.16 * 0.16 / 3.0);
        const float tph2  = (float)(TW * 0.16 * 0.16);
        const float n23tph2 = (float)(-TW * 2.0 * 0.16 * 0.16 / 3.0);
        const float ngam  = -gamma;
        const float nw2t  = -(omega * omega) * inv2pi;
        const float Atil  = A * omega * omega * inv2pi;

        const double c_d = 6.283185307179586476925287 * (double)phi;
        const float cdf  = (float)::cos(c_d * 0.16);
        const float sdf  = (float)::sin(c_d * 0.16);
        const float nsdf = -sdf;
        const float A2c  = Atil * (float)::cos(c_d * (0.16 / 3.0));
        const float nA2s = -Atil * (float)::sin(c_d * (0.16 / 3.0));
        const float A3c  = Atil * (float)::cos(c_d * (0.32 / 3.0));
        const float nA3s = -Atil * (float)::sin(c_d * (0.32 / 3.0));

        float rcf = 1.0f, rsf = 0.0f;
        float Un, Vn, rcn, rsn;

        for (int k4 = 0; k4 < 128; k4 += 4) {
#pragma unroll
            for (int j = 0; j < 4; ++j) {
                ring[k4 + j][lane] = make_float2(U, V);
                STEPP(); COMMIT();
            }
            // RELEASE orders the 4 ring writes above.
            if (lane == 0)
                __hip_atomic_store(&cnt, k4 + 4, __ATOMIC_RELEASE,
                                   __HIP_MEMORY_SCOPE_WORKGROUP);
        }
        ring[128][lane] = make_float2(U, V);            // final endpoint state
        if (lane == 0)
            __hip_atomic_store(&cnt, 129, __ATOMIC_RELEASE,
                               __HIP_MEMORY_SCOPE_WORKGROUP);
    } else if (wv <= 5) {
        // -------- 5 emitters: step-QUADS, 256B segments per row --------
        const int eid = wv - 1;             // 0..4
        float* __restrict__ stg = &stag[eid][0];
        const int r4 = lane >> 4;           // row within 4-row group
        const int q4 = lane & 15;           // 16B column chunk (16 per 64 cols)
        float* __restrict__ outblk = out + (size_t)(blockIdx.x * 64) * LEN_EPISODE;

        float va[64];

        for (int qd = eid; qd < 32; qd += 5) {
            const int k0 = qd << 2;         // first step of the quad
            // need states k0 .. k0+4
            while (__hip_atomic_load(&cnt, __ATOMIC_ACQUIRE,
                                     __HIP_MEMORY_SCOPE_WORKGROUP) < k0 + 5) {
                __builtin_amdgcn_s_sleep(2);
            }
            float2 s[5];
#pragma unroll
            for (int j = 0; j < 5; ++j) s[j] = ring[k0 + j][lane];

            va[0] = (k0 == 0) ? ic.x : twopi * s[0].x;  // previous endpoint
#pragma unroll
            for (int j = 0; j < 4; ++j) {
                const float U = s[j].x, V = s[j].y;
                const float Un = s[j + 1].x, Vn = s[j + 1].y;
                EMIT15(va + 16 * j + 1);
                if (j < 3) va[16 * j + 16] = twopi * Un;
            }

#pragma unroll
            for (int j = 0; j < 64; ++j)
                stg[j * 65 + lane] = va[j];

            const int colb = qd << 6;       // 64 contiguous output columns
#pragma unroll
            for (int rb = 0; rb < 16; ++rb) {
                const int row = (rb << 2) + r4;
                float4 v;
                v.x = stg[(4 * q4 + 0) * 65 + row];
                v.y = stg[(4 * q4 + 1) * 65 + row];
                v.z = stg[(4 * q4 + 2) * 65 + row];
                v.w = stg[(4 * q4 + 3) * 65 + row];
                *reinterpret_cast<float4*>(outblk + (size_t)row * LEN_EPISODE + colb + 4 * q4) = v;
            }
        }
    }
    // waves 6,7: exit after init barrier (emit capacity not binding, R28)
    // final endpoint (output index 2048) intentionally discarded
}

extern "C" void kernel_launch(void* const* d_in, const int* in_sizes, int n_in,
                              void* d_out, int out_size, void* d_ws, size_t ws_size,
                              hipStream_t stream) {
    const float* init   = (const float*)d_in[0];
    const float* params = (const float*)d_in[1];
    float* out = (float*)d_out;
    const int B = in_sizes[0] / 2;  // 16384

    const int block = 512;              // wave 0 producer, 5 emitter waves
    const int grid  = B / 64;           // 256 blocks, exact cover
    pend_kernel<<<grid, block, 0, stream>>>(init, params, out, B);
}